// Round 20
// baseline (105.342 us; speedup 1.0000x reference)
//
#include <hip/hip_runtime.h>
#include <hip/hip_bf16.h>
#include <stdint.h>

#define Bn 8
#define Cn 256
#define Hn 56
#define Wn 56
#define HWn 3136
#define NHEADS 8
#define HDIM 32
#define SEQ 392
#define NSTR 8
#define QKV_LD 768
// SCALE * log2(e): K is pre-scaled by this in the qkv-GEMM epilogue so the
// attention softmax can use exp2 with no per-score multiply.
#define KSC (0.17677669529663689f * 1.4426950408889634f)

#if __has_builtin(__builtin_amdgcn_exp2f)
#define EXP2(x) __builtin_amdgcn_exp2f(x)
#else
#define EXP2(x) exp2f(x)
#endif

typedef short short8 __attribute__((ext_vector_type(8)));
typedef float floatx4 __attribute__((ext_vector_type(4)));

__device__ __forceinline__ unsigned short f2bf(float f) {
  union { float f; uint32_t u; } v; v.f = f;
  uint32_t u = v.u;
  u += 0x7fffu + ((u >> 16) & 1u);   // RNE
  return (unsigned short)(u >> 16);
}
__device__ __forceinline__ float bf2f(unsigned short h) {
  union { uint32_t u; float f; } v; v.u = ((uint32_t)h) << 16;
  return v.f;
}
__device__ __forceinline__ uint32_t cvt_pk_bf16(float lo, float hi) {
  uint32_t r;
  asm("v_cvt_pk_bf16_f32 %0, %1, %2" : "=v"(r) : "v"(lo), "v"(hi));
  return r;
}
// async global->LDS, 16B per lane; LDS dest = wave-uniform base + lane*16
__device__ __forceinline__ void gload16(const unsigned short* g, unsigned short* l) {
  __builtin_amdgcn_global_load_lds((const __attribute__((address_space(1))) void*)g,
                                   (__attribute__((address_space(3))) void*)l, 16, 0, 0);
}

// ---------------- prep: weight cvt (blocks 0..255) + x transpose (blocks 256+) ----------------
__global__ __launch_bounds__(256) void k_prep(const float* __restrict__ wa,
                                              const float* __restrict__ wb,
                                              unsigned short* __restrict__ da,
                                              unsigned short* __restrict__ db,
                                              const float* __restrict__ x,
                                              unsigned short* __restrict__ xt) {
  int bx = blockIdx.x;
  int t = threadIdx.x;
  if (bx < 256) {
    int i = bx * 256 + t;   // 65536 float4 slots total
    if (i < 49152) {
      float4 v = ((const float4*)wa)[i];
      ushort4 o;
      o.x = f2bf(v.x); o.y = f2bf(v.y); o.z = f2bf(v.z); o.w = f2bf(v.w);
      ((ushort4*)da)[i] = o;
    } else {
      int k = i - 49152;
      float4 v = ((const float4*)wb)[k];
      ushort4 o;
      o.x = f2bf(v.x); o.y = f2bf(v.y); o.z = f2bf(v.z); o.w = f2bf(v.w);
      ((ushort4*)db)[k] = o;
    }
    return;
  }
  __shared__ float tile[32][33];
  int tx = bx - 256;
  int pb = tx % 98, cb = (tx / 98) & 7, b = tx / 784;
  int c = t >> 3, p4 = (t & 7) * 4;
  float4 v = *(const float4*)(x + (((size_t)b * Cn + cb * 32 + c) * HWn + pb * 32 + p4));
  tile[c][p4 + 0] = v.x; tile[c][p4 + 1] = v.y; tile[c][p4 + 2] = v.z; tile[c][p4 + 3] = v.w;
  __syncthreads();
  int p = t >> 3, c4 = (t & 7) * 4;
  ushort4 o;
  o.x = f2bf(tile[c4 + 0][p]); o.y = f2bf(tile[c4 + 1][p]);
  o.z = f2bf(tile[c4 + 2][p]); o.w = f2bf(tile[c4 + 3][p]);
  *(ushort4*)(xt + (((size_t)b * HWn + pb * 32 + p) * Cn + cb * 32 + c4)) = o;
}

// ---------------- qkv GEMM: 64x128 tiles, 256 threads, 24 KB LDS ----------------
// 2400 blocks (12 m x 25 n x 8 b), n-major + XCD chunking, depth-2 vmcnt(3).
// m-tile of 64 rows lies in ONE channel class (q/k/v); q/k tiles = 2 heads.
__global__ __launch_bounds__(256) void k_gemm0(const unsigned short* __restrict__ A,
                                               const unsigned short* __restrict__ Bt,
                                               const float* __restrict__ bias,
                                               unsigned short* __restrict__ qkh,
                                               unsigned short* __restrict__ outV) {
  const int K = 256, N = HWn;
  __shared__ __align__(16) unsigned short SH[12288];   // As[2][2048] + Bs[2][4096]
  unsigned short* As = SH;            // [2][2048]
  unsigned short* Bs = SH + 4096;     // [2][4096]
  int t = threadIdx.x;
  int raw = blockIdx.x;
  int chunk = gridDim.x >> 3;         // 300
  int wg = (raw & 7) * chunk + (raw >> 3);   // bijective (grid % 8 == 0)
  int b = wg / 300, r = wg % 300;
  int m0 = (r % 12) * 64, n0 = (r / 12) * 128;
  const unsigned short* Bb = Bt + (size_t)b * N * K;
  int lane = t & 63, w = t >> 6;      // 4 waves
  int wr = w >> 1, wc = w & 1;
  int g = lane >> 4, q = lane & 15;
  int rt = t >> 2, st = t & 3;        // staging row (0..63) / slot
  int cs = st ^ (rt & 3);
  const unsigned short* Ag = A + (size_t)(m0 + rt) * K + cs * 8;
  int nr0 = n0 + rt, nr1 = n0 + 64 + rt;
  const unsigned short* Bg0 = Bb + (size_t)((nr0 < N) ? nr0 : (N - 1)) * K + cs * 8;
  const unsigned short* Bg1 = Bb + (size_t)((nr1 < N) ? nr1 : (N - 1)) * K + cs * 8;
  int ldst = t * 8;

  floatx4 z4 = {0.f, 0.f, 0.f, 0.f};
  floatx4 acc[2][4];
#pragma unroll
  for (int i = 0; i < 2; i++)
#pragma unroll
    for (int j = 0; j < 4; j++) acc[i][j] = z4;

#define STAGE0(kt, off2, off4) do {                                            \
    gload16(Ag + (kt) * 32, &As[(off2) + ldst]);                               \
    gload16(Bg0 + (kt) * 32, &Bs[(off4) + ldst]);                              \
    gload16(Bg1 + (kt) * 32, &Bs[(off4) + 2048 + ldst]);                       \
  } while (0)

#define COMPUTE0(off2, off4) do {                                              \
    short8 af[2], bfr[4];                                                      \
    _Pragma("unroll")                                                          \
    for (int i = 0; i < 2; i++) {                                              \
      int row = wr * 32 + i * 16 + q;                                          \
      af[i] = *(const short8*)&As[(off2) + row * 32 + ((g ^ (q & 3)) << 3)];   \
    }                                                                          \
    _Pragma("unroll")                                                          \
    for (int j = 0; j < 4; j++) {                                              \
      int row = wc * 64 + j * 16 + q;                                          \
      bfr[j] = *(const short8*)&Bs[(off4) + row * 32 + ((g ^ (q & 3)) << 3)];  \
    }                                                                          \
    _Pragma("unroll")                                                          \
    for (int i = 0; i < 2; i++)                                                \
      _Pragma("unroll")                                                        \
      for (int j = 0; j < 4; j++)                                              \
        acc[i][j] = __builtin_amdgcn_mfma_f32_16x16x32_bf16(af[i], bfr[j], acc[i][j], 0, 0, 0); \
  } while (0)

  STAGE0(0, 0, 0);
  STAGE0(1, 2048, 4096);
#pragma unroll
  for (int tt = 0; tt < 8; tt++) {
    if (tt < 7) { asm volatile("s_waitcnt vmcnt(3)" ::: "memory"); }
    else       { asm volatile("s_waitcnt vmcnt(0)" ::: "memory"); }
    __syncthreads();
    COMPUTE0((tt & 1) * 2048, (tt & 1) * 4096);
    __syncthreads();
    if (tt < 6) STAGE0(tt + 2, (tt & 1) * 2048, (tt & 1) * 4096);
  }
#undef STAGE0
#undef COMPUTE0

  // ---- LDS-transposed epilogue: E[col 128][8 granules x 8ch], XOR-swizzled ----
  unsigned short* E = SH;   // 16384 B needed, 24576 available
#pragma unroll
  for (int i = 0; i < 2; i++) {
    int ob = m0 + wr * 32 + i * 16 + g * 4;
    float bs0 = bias[ob + 0], bs1 = bias[ob + 1], bs2 = bias[ob + 2], bs3 = bias[ob + 3];
    float sc = (m0 >= 256 && m0 < 512) ? KSC : 1.0f;
    int lobg = wr * 4 + i * 2 + (g >> 1);   // 0..7
#pragma unroll
    for (int j = 0; j < 4; j++) {
      int lc = wc * 64 + j * 16 + q;
      ushort4 o;
      o.x = f2bf((acc[i][j][0] + bs0) * sc);
      o.y = f2bf((acc[i][j][1] + bs1) * sc);
      o.z = f2bf((acc[i][j][2] + bs2) * sc);
      o.w = f2bf((acc[i][j][3] + bs3) * sc);
      *(ushort4*)&E[lc * 64 + ((lobg ^ (lc & 7)) << 3) + (g & 1) * 4] = o;
    }
  }
  __syncthreads();
  int c = t >> 1, part = t & 1;
  int col = n0 + c;
  if (col < N) {
    unsigned short* dst;
    if (m0 < 512) {              // q,k head-panels: tile = 2 heads
      int hd = ((m0 & 255) >> 5) + part;
      int sl = ((m0 >= 256) ? 8 : 0) + hd;
      int p_ord = (hd >= 4) ? ((col % Wn) * Wn + col / Wn) : col;
      dst = qkh + (((size_t)b * 16 + sl) * HWn + p_ord) * 32;
    } else {                     // v pixel-major
      dst = outV + ((size_t)b * HWn + col) * 256 + (m0 - 512) + part * 32;
    }
#pragma unroll
    for (int k2 = part * 4; k2 < part * 4 + 4; k2++) {   // 32 chans = 64B contiguous
      short8 v = *(const short8*)&E[c * 64 + ((k2 ^ (c & 7)) << 3)];
      *(short8*)(dst + (k2 - part * 4) * 8) = v;
    }
  }
}

// ---------------- proj GEMM (M=256, K=256, BK=64) ----------------
__global__ __launch_bounds__(512) void k_gemm1(const unsigned short* __restrict__ A,
                                               const unsigned short* __restrict__ Bt,
                                               const float* __restrict__ bias,
                                               float* __restrict__ outF,
                                               int M, int N, int nm, int nper) {
  const int K = 256;
  __shared__ __align__(16) char SH[67584];
  unsigned short* As = (unsigned short*)SH;   // [2][8192]
  unsigned short* Bs = As + 16384;            // [2][8192]
  int t = threadIdx.x;
  int raw = blockIdx.x;
  int chunk = gridDim.x >> 3;
  int wg = (raw & 7) * chunk + (raw >> 3);
  int b = wg / nper, r = wg % nper;
  int m0 = (r % nm) * 128, n0 = (r / nm) * 128;
  const unsigned short* Bb = Bt + (size_t)b * N * K;
  int lane = t & 63, w = t >> 6;
  int wr = w >> 1, wc = w & 1;
  int g = lane >> 4, q = lane & 15;
  int srow8 = lane >> 3;
  int slot = lane & 7;

  const unsigned short* Ag[2];
  const unsigned short* Bg[2];
  int ldst[2];
#pragma unroll
  for (int i = 0; i < 2; i++) {
    int row = i * 64 + w * 8 + srow8;
    int cs = slot ^ srow8;
    Ag[i] = A + (size_t)(m0 + row) * K + cs * 8;
    int nr = n0 + row;
    Bg[i] = Bb + (size_t)((nr < N) ? nr : (N - 1)) * K + cs * 8;
    ldst[i] = (i * 64 + w * 8) * 64;
  }

  floatx4 z4 = {0.f, 0.f, 0.f, 0.f};
  floatx4 acc[2][4];
#pragma unroll
  for (int i = 0; i < 2; i++)
#pragma unroll
    for (int j = 0; j < 4; j++) acc[i][j] = z4;

#define STAGE(kt, off) do {                                                    \
    _Pragma("unroll")                                                          \
    for (int i = 0; i < 2; i++) gload16(Ag[i] + (kt) * 64, &As[(off) + ldst[i]]); \
    _Pragma("unroll")                                                          \
    for (int i = 0; i < 2; i++) gload16(Bg[i] + (kt) * 64, &Bs[(off) + ldst[i]]); \
  } while (0)

#define COMPUTE(off) do {                                                      \
    _Pragma("unroll")                                                          \
    for (int kk = 0; kk < 64; kk += 32) {                                      \
      short8 af[2], bfr[4];                                                    \
      _Pragma("unroll")                                                        \
      for (int i = 0; i < 2; i++) {                                            \
        int row = wr * 32 + i * 16 + q;                                        \
        af[i] = *(const short8*)&As[(off) + row * 64 + ((((kk >> 3) + g) ^ (q & 7)) << 3)]; \
      }                                                                        \
      _Pragma("unroll")                                                        \
      for (int j = 0; j < 4; j++) {                                            \
        int row = wc * 64 + j * 16 + q;                                        \
        bfr[j] = *(const short8*)&Bs[(off) + row * 64 + ((((kk >> 3) + g) ^ (q & 7)) << 3)]; \
      }                                                                        \
      _Pragma("unroll")                                                        \
      for (int i = 0; i < 2; i++)                                              \
        _Pragma("unroll")                                                      \
        for (int j = 0; j < 4; j++)                                            \
          acc[i][j] = __builtin_amdgcn_mfma_f32_16x16x32_bf16(af[i], bfr[j], acc[i][j], 0, 0, 0); \
    }                                                                          \
  } while (0)

  STAGE(0, 0);
  STAGE(1, 8192);
  asm volatile("s_waitcnt vmcnt(4)" ::: "memory");
  __syncthreads();
  COMPUTE(0);
  __syncthreads();
  STAGE(2, 0);
  asm volatile("s_waitcnt vmcnt(4)" ::: "memory");
  __syncthreads();
  COMPUTE(8192);
  __syncthreads();
  STAGE(3, 8192);
  asm volatile("s_waitcnt vmcnt(4)" ::: "memory");
  __syncthreads();
  COMPUTE(0);
  asm volatile("s_waitcnt vmcnt(0)" ::: "memory");
  __syncthreads();
  COMPUTE(8192);
#undef STAGE
#undef COMPUTE

  __syncthreads();
  float* Ef = (float*)SH;   // [row 128][132]
#pragma unroll
  for (int i = 0; i < 2; i++) {
    int ob = m0 + wr * 32 + i * 16 + g * 4;
    int lob = wr * 32 + i * 16 + g * 4;
    float bs0 = bias[ob + 0], bs1 = bias[ob + 1], bs2 = bias[ob + 2], bs3 = bias[ob + 3];
#pragma unroll
    for (int j = 0; j < 4; j++) {
      int lc = wc * 64 + j * 16 + q;
      Ef[(lob + 0) * 132 + lc] = acc[i][j][0] + bs0;
      Ef[(lob + 1) * 132 + lc] = acc[i][j][1] + bs1;
      Ef[(lob + 2) * 132 + lc] = acc[i][j][2] + bs2;
      Ef[(lob + 3) * 132 + lc] = acc[i][j][3] + bs3;
    }
  }
  __syncthreads();
  int rr = t >> 2, seg = t & 3;
  float* dst = outF + (size_t)b * M * N + (size_t)(m0 + rr) * N + n0;
#pragma unroll
  for (int k2 = 0; k2 < 8; k2++) {
    int col = seg * 32 + k2 * 4;
    if (n0 + col < N) {
      floatx4 v = *(const floatx4*)&Ef[rr * 132 + col];
      *(floatx4*)(dst + col) = v;
    }
  }
}

// ---------------- depthwise 3x3 on v (vb[b][px][256]), output vmt[b][ch][pixel] ----------------
__global__ __launch_bounds__(512) void k_dwconv_t(const unsigned short* __restrict__ vb,
                                                  const float* __restrict__ wdw,
                                                  const float* __restrict__ bdw,
                                                  unsigned short* __restrict__ vmt) {
  __shared__ float wS[1152];
  __shared__ float bS[128];
  __shared__ __align__(16) unsigned short tile[32][140];
  int t = threadIdx.x;
  int pass = blockIdx.y, b = blockIdx.z;
  for (int i = t; i < 1152; i += 512) wS[i] = wdw[pass * 1152 + i];
  if (t < 128) bS[t] = bdw[pass * 128 + t];
  __syncthreads();

  int pi = t >> 4, c8 = (t & 15) * 8;
  int i32 = blockIdx.x * 32 + pi;
  int h, w;
  if (pass == 0) { h = i32 / Wn; w = i32 % Wn; }
  else           { w = i32 / Hn; h = i32 % Hn; }

  const unsigned short* vq = vb + pass * 128 + c8;
  float a[8];
  short8 vc = *(const short8*)(vq + ((size_t)b * HWn + h * Wn + w) * 256);
#pragma unroll
  for (int e = 0; e < 8; e++) a[e] = bf2f((unsigned short)vc[e]) + bS[c8 + e];
#pragma unroll
  for (int ky = 0; ky < 3; ky++) {
    int hh = h + ky - 1;
    if (hh < 0 || hh >= Hn) continue;
#pragma unroll
    for (int kx = 0; kx < 3; kx++) {
      int ww = w + kx - 1;
      if (ww < 0 || ww >= Wn) continue;
      short8 vn = *(const short8*)(vq + ((size_t)b * HWn + hh * Wn + ww) * 256);
#pragma unroll
      for (int e = 0; e < 8; e++) a[e] += bf2f((unsigned short)vn[e]) * wS[(c8 + e) * 9 + ky * 3 + kx];
    }
  }
  short8 o;
#pragma unroll
  for (int e = 0; e < 8; e++) o[e] = (short)f2bf(a[e]);
  *(short8*)&tile[pi][c8] = o;
  __syncthreads();

  int dd = t >> 2, quarter = t & 3;
  short8 ov;
#pragma unroll
  for (int k2 = 0; k2 < 8; k2++) ov[k2] = (short)tile[quarter * 8 + k2][dd];
  *(short8*)(vmt + ((size_t)(b * Cn + pass * 128 + dd)) * HWn + blockIdx.x * 32 + quarter * 8) = ov;
}

// ---------------- stripe attention (two-phase scores: peak 52 score VGPRs) ----------------
// grid: (stripe 0..7, b*8+hd 0..63), 512 threads (8 waves)
__global__ __launch_bounds__(512) void k_attn(const unsigned short* __restrict__ qkh,
                                              const unsigned short* __restrict__ vmt,
                                              unsigned short* __restrict__ aout) {
  __shared__ __align__(16) unsigned short Ks[12288];  // 24 j * 4 g * 16 q granules
  __shared__ __align__(16) unsigned short Vf[12800];  // 50 Gc * 32 d granules (d swizzled)
  __shared__ __align__(16) unsigned short Pf[4096];   // 8 waves * 4 Gl * 16 q granules
  int s = blockIdx.x;
  int hd = blockIdx.y & 7, b = blockIdx.y >> 3;
  int t = threadIdx.x, lane = t & 63, wv = t >> 6;
  bool wst = (hd >= 4);
  int q = lane & 15, g = lane >> 4;
  int sbase = s * SEQ;

  const unsigned short* qh = qkh + (((size_t)b * 16 + hd) * HWn + sbase) * 32;
  const unsigned short* kh = qkh + (((size_t)b * 16 + 8 + hd) * HWn + sbase) * 32;

  // ---- Q prefetch ----
  short8 qpre[4];
#pragma unroll
  for (int it = 0; it < 4; it++) {
    int qb = it * 8 + wv;
    int qi = qb * 16 + q;
    int qil = (qi < SEQ) ? qi : 391;
    qpre[it] = *(const short8*)(qh + (size_t)qil * 32 + g * 8);
  }

  // ---- stage K keys 0..383, fragment-major ----
#pragma unroll
  for (int P = 0; P < 3; P++) {
    int key = P * 128 + (t >> 2);
    int gg = t & 3;
    short8 kv = *(const short8*)(kh + (size_t)key * 32 + gg * 8);
    *(short8*)&Ks[((((key >> 4) * 4 + gg) * 16) + (key & 15)) * 8] = kv;
  }
  short8 kf24;
  {
    int key = 384 + q; if (key > 391) key = 391;
    kf24 = *(const short8*)(kh + (size_t)key * 32 + g * 8);
  }
  // ---- stage V fragment-major with d-swizzle ----
  const unsigned short* vg = vmt + ((size_t)(b * Cn + hd * HDIM)) * HWn + sbase;
  for (int idx = t; idx < 1600; idx += 512) {
    int d = idx / 50, Gc = idx % 50;
    short8 vv = *(const short8*)(vg + (size_t)d * HWn + Gc * 8);
    *(short8*)&Vf[(Gc * 32 + (d ^ (Gc & 7))) * 8] = vv;
  }
  __syncthreads();

  floatx4 z4 = {0.f, 0.f, 0.f, 0.f};
  unsigned short* Pw = &Pf[wv * 512];
  int gh = g >> 1, ge = (g & 1) * 4;

#pragma unroll
  for (int it = 0; it < 4; it++) {
    int qb = it * 8 + wv;
    if (qb >= 25) continue;
    int qi = qb * 16 + q;
    int qil = (qi < SEQ) ? qi : 391;
    short8 qf = qpre[it];

    floatx4 sph[13];
    float sm = 0.f;
    floatx4 o0 = z4, o1 = z4;

// write P chunk for sacc pair (arrA, idxA valid; arrB may be the zero tail)
#define WRITEPX(sA_, sB_, validB) do {                                         \
    uint2 wA, wB;                                                              \
    wA.x = cvt_pk_bf16((sA_)[0], (sA_)[1]);                                    \
    wA.y = cvt_pk_bf16((sA_)[2], (sA_)[3]);                                    \
    if (validB) {                                                              \
      wB.x = cvt_pk_bf16((sB_)[0], (sB_)[1]);                                  \
      wB.y = cvt_pk_bf16((sB_)[2], (sB_)[3]);                                  \
    } else { wB.x = 0u; wB.y = 0u; }                                           \
    *(uint2*)&Pw[(gh * 16 + q) * 8 + ge] = wA;                                 \
    *(uint2*)&Pw[((2 + gh) * 16 + q) * 8 + ge] = wB;                           \
  } while (0)

#define PVSTEP(ch) do {                                                        \
    asm volatile("s_waitcnt lgkmcnt(0)" ::: "memory");                         \
    short8 pfr = *(const short8*)&Pw[(g * 16 + q) * 8];                        \
    int Gc = (ch) * 4 + g; if (Gc > 49) Gc = 49;                               \
    int sw = Gc & 7;                                                           \
    short8 vf0 = *(const short8*)&Vf[(Gc * 32 + (q ^ sw)) * 8];                \
    short8 vf1 = *(const short8*)&Vf[(Gc * 32 + 16 + (q ^ sw)) * 8];           \
    pfr_ = pfr; vf0_ = vf0; vf1_ = vf1;                                        \
  } while (0)

    short8 pfr_, vf0_, vf1_;

    // ======== phase A: j 0..11 (chunks 0..5) ========
    __builtin_amdgcn_s_setprio(1);
#pragma unroll
    for (int j = 0; j < 12; j++) {
      short8 kf = *(const short8*)&Ks[((j * 4 + g) * 16 + q) * 8];
      sph[j] = __builtin_amdgcn_mfma_f32_16x16x32_bf16(kf, qf, z4, 0, 0, 0);
    }
    __builtin_amdgcn_s_setprio(0);
#pragma unroll
    for (int j = 0; j < 12; j++) {
      float e0 = EXP2(sph[j][0]); float e1 = EXP2(sph[j][1]);
      float e2 = EXP2(sph[j][2]); float e3 = EXP2(sph[j][3]);
      sph[j][0] = e0; sph[j][1] = e1; sph[j][2] = e2; sph[j][3] = e3;
      sm += (e0 + e1) + (e2 + e3);
    }
    WRITEPX(sph[0], sph[1], true);
#pragma unroll
    for (int ch = 0; ch < 6; ch++) {
      PVSTEP(ch);
      if (ch < 5) {
        switch (ch + 1) {
          case 1: WRITEPX(sph[2], sph[3], true); break;
          case 2: WRITEPX(sph[4], sph[5], true); break;
          case 3: WRITEPX(sph[6], sph[7], true); break;
          case 4: WRITEPX(sph[8], sph[9], true); break;
          case 5: WRITEPX(sph[10], sph[11], true); break;
        }
      }
      __builtin_amdgcn_s_setprio(1);
      o0 = __builtin_amdgcn_mfma_f32_16x16x32_bf16(vf0_, pfr_, o0, 0, 0, 0);
      o1 = __builtin_amdgcn_mfma_f32_16x16x32_bf16(vf1_, pfr_, o1, 0, 0, 0);
      __builtin_amdgcn_s_setprio(0);
    }

    // ======== phase B: j 12..24 (chunks 6..12) ========
    __builtin_amdgcn_s_setprio(1);
#pragma unroll
    for (int j = 0; j < 12; j++) {
      short8 kf = *(const short8*)&Ks[(((j + 12) * 4 + g) * 16 + q) * 8];
      sph[j] = __builtin_amdgcn_mfma_f32_16x16x32_bf16(kf, qf, z4, 0, 0, 0);
    }
    sph[12] = __builtin_amdgcn_mfma_f32_16x16x32_bf16(kf24, qf, z4, 0, 0, 0);
    __builtin_amdgcn_s_setprio(0);
    if (g >= 2) { sph[12][0] = sph[12][1] = sph[12][2] = sph[12][3] = -3.0e38f; }
#pragma unroll
    for (int j = 0; j < 13; j++) {
      float e0 = EXP2(sph[j][0]); float e1 = EXP2(sph[j][1]);
      float e2 = EXP2(sph[j][2]); float e3 = EXP2(sph[j][3]);
      sph[j][0] = e0; sph[j][1] = e1; sph[j][2] = e2; sph[j][3] = e3;
      sm += (e0 + e1) + (e2 + e3);
    }
    WRITEPX(sph[0], sph[1], true);
#pragma unroll
    for (int ch = 6; ch < 13; ch++) {
      PVSTEP(ch);
      if (ch < 12) {
        switch (ch + 1) {
          case 7:  WRITEPX(sph[2], sph[3], true); break;
          case 8:  WRITEPX(sph[4], sph[5], true); break;
          case 9:  WRITEPX(sph[6], sph[7], true); break;
          case 10: WRITEPX(sph[8], sph[9], true); break;
          case 11: WRITEPX(sph[10], sph[11], true); break;
          case 12: WRITEPX(sph[12], sph[12], false); break;
        }
      }
      __builtin_amdgcn_s_setprio(1);
      o0 = __builtin_amdgcn_mfma_f32_16x16x32_bf16(vf0_, pfr_, o0, 0, 0, 0);
      o1 = __builtin_amdgcn_mfma_f32_16x16x32_bf16(vf1_, pfr_, o1, 0, 0, 0);
      __builtin_amdgcn_s_setprio(0);
    }
#undef WRITEPX
#undef PVSTEP

    sm += __shfl_xor(sm, 16);
    sm += __shfl_xor(sm, 32);
    float rcp = 1.0f / sm;

    if (qi < SEQ) {
      int pq = wst ? ((qil % Wn) * Wn + s * 7 + qil / Wn) : (sbase + qil);
      size_t ob = ((size_t)b * HWn + pq) * Cn + hd * HDIM;
      ushort4 u0, u1;
      u0.x = f2bf(o0[0] * rcp); u0.y = f2bf(o0[1] * rcp);
      u0.z = f2bf(o0[2] * rcp); u0.w = f2bf(o0[3] * rcp);
      u1.x = f2bf(o1[0] * rcp); u1.y = f2bf(o1[1] * rcp);
      u1.z = f2bf(o1[2] * rcp); u1.w = f2bf(o1[3] * rcp);
      *(ushort4*)(aout + ob + g * 4) = u0;
      *(ushort4*)(aout + ob + 16 + g * 4) = u1;
    }
  }
}

extern "C" void kernel_launch(void* const* d_in, const int* in_sizes, int n_in,
                              void* d_out, int out_size, void* d_ws, size_t ws_size,
                              hipStream_t stream) {
  const float* x     = (const float*)d_in[0];
  const float* wqkv  = (const float*)d_in[1];
  const float* bqkv  = (const float*)d_in[2];
  const float* wdw   = (const float*)d_in[3];
  const float* bdw   = (const float*)d_in[4];
  const float* wproj = (const float*)d_in[5];
  const float* bproj = (const float*)d_in[6];
  float* out = (float*)d_out;

  unsigned short* xt   = (unsigned short*)d_ws;                    // [B][HW][256] bf16
  unsigned short* wqb  = xt + (size_t)Bn * HWn * Cn;               // [768][256]
  unsigned short* wpb  = wqb + 768 * 256;                          // [256][256]
  unsigned short* qkh  = wpb + 256 * 256;                          // [B][16][HW][32] head-panels
  unsigned short* vb   = qkh + (size_t)Bn * 16 * HWn * 32;         // [B][HW][256] v pixel-major
  unsigned short* vmt  = vb + (size_t)Bn * HWn * Cn;               // [B][256ch][HW]
  unsigned short* aout = vmt + (size_t)Bn * HWn * Cn;              // [B][HW][256]

  k_prep<<<dim3(256 + 98 * 8 * Bn), 256, 0, stream>>>(wqkv, wproj, wqb, wpb, x, xt);
  k_gemm0<<<dim3(2400), 256, 0, stream>>>(wqb, xt, bqkv, qkh, vb);
  k_dwconv_t<<<dim3(98, 2, Bn), 512, 0, stream>>>(vb, wdw, bdw, vmt);
  k_attn<<<dim3(NSTR, Bn * NHEADS), 512, 0, stream>>>(qkh, vmt, aout);
  k_gemm1<<<dim3(400), 512, 0, stream>>>(wpb, aout, bproj, out, 256, HWn, 2, 50);
}

// Round 21
// 102.288 us; speedup vs baseline: 1.0299x; 1.0299x over previous
//
#include <hip/hip_runtime.h>
#include <hip/hip_bf16.h>
#include <stdint.h>

#define Bn 8
#define Cn 256
#define Hn 56
#define Wn 56
#define HWn 3136
#define NHEADS 8
#define HDIM 32
#define SEQ 392
#define NSTR 8
#define QKV_LD 768
// SCALE * log2(e): K is pre-scaled by this in the qkv-GEMM epilogue so the
// attention softmax can use exp2 with no per-score multiply.
#define KSC (0.17677669529663689f * 1.4426950408889634f)

#if __has_builtin(__builtin_amdgcn_exp2f)
#define EXP2(x) __builtin_amdgcn_exp2f(x)
#else
#define EXP2(x) exp2f(x)
#endif

typedef short short8 __attribute__((ext_vector_type(8)));
typedef float floatx4 __attribute__((ext_vector_type(4)));

__device__ __forceinline__ unsigned short f2bf(float f) {
  union { float f; uint32_t u; } v; v.f = f;
  uint32_t u = v.u;
  u += 0x7fffu + ((u >> 16) & 1u);   // RNE
  return (unsigned short)(u >> 16);
}
__device__ __forceinline__ float bf2f(unsigned short h) {
  union { uint32_t u; float f; } v; v.u = ((uint32_t)h) << 16;
  return v.f;
}
__device__ __forceinline__ uint32_t cvt_pk_bf16(float lo, float hi) {
  uint32_t r;
  asm("v_cvt_pk_bf16_f32 %0, %1, %2" : "=v"(r) : "v"(lo), "v"(hi));
  return r;
}
// async global->LDS, 16B per lane; LDS dest = wave-uniform base + lane*16
__device__ __forceinline__ void gload16(const unsigned short* g, unsigned short* l) {
  __builtin_amdgcn_global_load_lds((const __attribute__((address_space(1))) void*)g,
                                   (__attribute__((address_space(3))) void*)l, 16, 0, 0);
}

// ---------------- prep: weight cvt (blocks 0..255) + x transpose (blocks 256+) ----------------
__global__ __launch_bounds__(256) void k_prep(const float* __restrict__ wa,
                                              const float* __restrict__ wb,
                                              unsigned short* __restrict__ da,
                                              unsigned short* __restrict__ db,
                                              const float* __restrict__ x,
                                              unsigned short* __restrict__ xt) {
  int bx = blockIdx.x;
  int t = threadIdx.x;
  if (bx < 256) {
    int i = bx * 256 + t;   // 65536 float4 slots total
    if (i < 49152) {
      float4 v = ((const float4*)wa)[i];
      ushort4 o;
      o.x = f2bf(v.x); o.y = f2bf(v.y); o.z = f2bf(v.z); o.w = f2bf(v.w);
      ((ushort4*)da)[i] = o;
    } else {
      int k = i - 49152;
      float4 v = ((const float4*)wb)[k];
      ushort4 o;
      o.x = f2bf(v.x); o.y = f2bf(v.y); o.z = f2bf(v.z); o.w = f2bf(v.w);
      ((ushort4*)db)[k] = o;
    }
    return;
  }
  __shared__ float tile[32][33];
  int tx = bx - 256;
  int pb = tx % 98, cb = (tx / 98) & 7, b = tx / 784;
  int c = t >> 3, p4 = (t & 7) * 4;
  float4 v = *(const float4*)(x + (((size_t)b * Cn + cb * 32 + c) * HWn + pb * 32 + p4));
  tile[c][p4 + 0] = v.x; tile[c][p4 + 1] = v.y; tile[c][p4 + 2] = v.z; tile[c][p4 + 3] = v.w;
  __syncthreads();
  int p = t >> 3, c4 = (t & 7) * 4;
  ushort4 o;
  o.x = f2bf(tile[c4 + 0][p]); o.y = f2bf(tile[c4 + 1][p]);
  o.z = f2bf(tile[c4 + 2][p]); o.w = f2bf(tile[c4 + 3][p]);
  *(ushort4*)(xt + (((size_t)b * HWn + pb * 32 + p) * Cn + cb * 32 + c4)) = o;
}

// ---------------- qkv GEMM (M=768, K=256, BK=32): 32 KB LDS ----------------
__global__ __launch_bounds__(512) void k_gemm0(const unsigned short* __restrict__ A,
                                               const unsigned short* __restrict__ Bt,
                                               const float* __restrict__ bias,
                                               unsigned short* __restrict__ qkh,
                                               unsigned short* __restrict__ outV) {
  const int K = 256, N = HWn;
  __shared__ __align__(16) unsigned short SH[16384];   // As[2][4096] + Bs[2][4096]
  unsigned short* As = SH;
  unsigned short* Bs = SH + 8192;
  int t = threadIdx.x;
  int raw = blockIdx.x;
  int chunk = gridDim.x >> 3;
  int wg = (raw & 7) * chunk + (raw >> 3);     // bijective (grid % 8 == 0)
  int b = wg / 150, r = wg % 150;
  int m0 = (r % 6) * 128, n0 = (r / 6) * 128;
  const unsigned short* Bb = Bt + (size_t)b * N * K;
  int lane = t & 63, w = t >> 6;
  int wr = w >> 1, wc = w & 1;
  int g = lane >> 4, q = lane & 15;
  int rt = t >> 2, st = t & 3;                 // staging row / slot
  int cs = st ^ (rt & 3);
  const unsigned short* Ag = A + (size_t)(m0 + rt) * K + cs * 8;
  int nr = n0 + rt;
  const unsigned short* Bg = Bb + (size_t)((nr < N) ? nr : (N - 1)) * K + cs * 8;
  int ldst = t * 8;

  floatx4 z4 = {0.f, 0.f, 0.f, 0.f};
  floatx4 acc[2][4];
#pragma unroll
  for (int i = 0; i < 2; i++)
#pragma unroll
    for (int j = 0; j < 4; j++) acc[i][j] = z4;

#define STAGE0(kt, off) do {                                                   \
    gload16(Ag + (kt) * 32, &As[(off) + ldst]);                                \
    gload16(Bg + (kt) * 32, &Bs[(off) + ldst]);                                \
  } while (0)

#define COMPUTE0(off) do {                                                     \
    short8 af[2], bfr[4];                                                      \
    _Pragma("unroll")                                                          \
    for (int i = 0; i < 2; i++) {                                              \
      int row = wr * 32 + i * 16 + q;                                          \
      af[i] = *(const short8*)&As[(off) + row * 32 + ((g ^ (q & 3)) << 3)];    \
    }                                                                          \
    _Pragma("unroll")                                                          \
    for (int j = 0; j < 4; j++) {                                              \
      int row = wc * 64 + j * 16 + q;                                          \
      bfr[j] = *(const short8*)&Bs[(off) + row * 32 + ((g ^ (q & 3)) << 3)];   \
    }                                                                          \
    _Pragma("unroll")                                                          \
    for (int i = 0; i < 2; i++)                                                \
      _Pragma("unroll")                                                        \
      for (int j = 0; j < 4; j++)                                              \
        acc[i][j] = __builtin_amdgcn_mfma_f32_16x16x32_bf16(af[i], bfr[j], acc[i][j], 0, 0, 0); \
  } while (0)

  STAGE0(0, 0);
  STAGE0(1, 4096);
#pragma unroll
  for (int tt = 0; tt < 8; tt++) {
    if (tt < 7) { asm volatile("s_waitcnt vmcnt(2)" ::: "memory"); }
    else       { asm volatile("s_waitcnt vmcnt(0)" ::: "memory"); }
    __syncthreads();
    COMPUTE0((tt & 1) * 4096);
    __syncthreads();
    if (tt < 6) STAGE0(tt + 2, (tt & 1) * 4096);
  }
#undef STAGE0
#undef COMPUTE0

  // ---- LDS-transposed epilogue: E[col 128][16 granules x 8ch], XOR-swizzled ----
  unsigned short* E = SH;   // 32768 B, exactly fits
#pragma unroll
  for (int i = 0; i < 2; i++) {
    int ob = m0 + wr * 32 + i * 16 + g * 4;
    float bs0 = bias[ob + 0], bs1 = bias[ob + 1], bs2 = bias[ob + 2], bs3 = bias[ob + 3];
    float sc = (ob >= 256 && ob < 512) ? KSC : 1.0f;
    int lobg = wr * 4 + i * 2 + (g >> 1);
#pragma unroll
    for (int j = 0; j < 4; j++) {
      int lc = wc * 64 + j * 16 + q;
      ushort4 o;
      o.x = f2bf((acc[i][j][0] + bs0) * sc);
      o.y = f2bf((acc[i][j][1] + bs1) * sc);
      o.z = f2bf((acc[i][j][2] + bs2) * sc);
      o.w = f2bf((acc[i][j][3] + bs3) * sc);
      *(ushort4*)&E[lc * 128 + ((lobg ^ (lc & 7)) << 3) + (g & 1) * 4] = o;
    }
  }
  __syncthreads();
  int c = t >> 2, part = t & 3;
  int col = n0 + c;
  if (col < N) {
    int mt = m0 >> 7;            // 0..5
    unsigned short* dst;
    if (mt < 4) {                // q,k head-panels
      int hd = (mt & 1) * 4 + part;
      int sl = (mt >> 1) * 8 + hd;           // isK*8 + head
      int p_ord = (hd >= 4) ? ((col % Wn) * Wn + col / Wn) : col;
      dst = qkh + (((size_t)b * 16 + sl) * HWn + p_ord) * 32;
    } else {                     // v pixel-major
      dst = outV + ((size_t)b * HWn + col) * 256 + (m0 - 512) + part * 32;
    }
#pragma unroll
    for (int k2 = part * 4; k2 < part * 4 + 4; k2++) {   // 32 chans = 64B contiguous
      short8 v = *(const short8*)&E[c * 128 + ((k2 ^ (c & 7)) << 3)];
      *(short8*)(dst + (k2 - part * 4) * 8) = v;
    }
  }
}

// ---------------- proj GEMM (M=256, K=256, BK=64) ----------------
__global__ __launch_bounds__(512) void k_gemm1(const unsigned short* __restrict__ A,
                                               const unsigned short* __restrict__ Bt,
                                               const float* __restrict__ bias,
                                               float* __restrict__ outF,
                                               int M, int N, int nm, int nper) {
  const int K = 256;
  __shared__ __align__(16) char SH[67584];
  unsigned short* As = (unsigned short*)SH;   // [2][8192]
  unsigned short* Bs = As + 16384;            // [2][8192]
  int t = threadIdx.x;
  int raw = blockIdx.x;
  int chunk = gridDim.x >> 3;
  int wg = (raw & 7) * chunk + (raw >> 3);
  int b = wg / nper, r = wg % nper;
  int m0 = (r % nm) * 128, n0 = (r / nm) * 128;
  const unsigned short* Bb = Bt + (size_t)b * N * K;
  int lane = t & 63, w = t >> 6;
  int wr = w >> 1, wc = w & 1;
  int g = lane >> 4, q = lane & 15;
  int srow8 = lane >> 3;
  int slot = lane & 7;

  const unsigned short* Ag[2];
  const unsigned short* Bg[2];
  int ldst[2];
#pragma unroll
  for (int i = 0; i < 2; i++) {
    int row = i * 64 + w * 8 + srow8;
    int cs = slot ^ srow8;
    Ag[i] = A + (size_t)(m0 + row) * K + cs * 8;
    int nr = n0 + row;
    Bg[i] = Bb + (size_t)((nr < N) ? nr : (N - 1)) * K + cs * 8;
    ldst[i] = (i * 64 + w * 8) * 64;
  }

  floatx4 z4 = {0.f, 0.f, 0.f, 0.f};
  floatx4 acc[2][4];
#pragma unroll
  for (int i = 0; i < 2; i++)
#pragma unroll
    for (int j = 0; j < 4; j++) acc[i][j] = z4;

#define STAGE(kt, off) do {                                                    \
    _Pragma("unroll")                                                          \
    for (int i = 0; i < 2; i++) gload16(Ag[i] + (kt) * 64, &As[(off) + ldst[i]]); \
    _Pragma("unroll")                                                          \
    for (int i = 0; i < 2; i++) gload16(Bg[i] + (kt) * 64, &Bs[(off) + ldst[i]]); \
  } while (0)

#define COMPUTE(off) do {                                                      \
    _Pragma("unroll")                                                          \
    for (int kk = 0; kk < 64; kk += 32) {                                      \
      short8 af[2], bfr[4];                                                    \
      _Pragma("unroll")                                                        \
      for (int i = 0; i < 2; i++) {                                            \
        int row = wr * 32 + i * 16 + q;                                        \
        af[i] = *(const short8*)&As[(off) + row * 64 + ((((kk >> 3) + g) ^ (q & 7)) << 3)]; \
      }                                                                        \
      _Pragma("unroll")                                                        \
      for (int j = 0; j < 4; j++) {                                            \
        int row = wc * 64 + j * 16 + q;                                        \
        bfr[j] = *(const short8*)&Bs[(off) + row * 64 + ((((kk >> 3) + g) ^ (q & 7)) << 3)]; \
      }                                                                        \
      _Pragma("unroll")                                                        \
      for (int i = 0; i < 2; i++)                                              \
        _Pragma("unroll")                                                      \
        for (int j = 0; j < 4; j++)                                            \
          acc[i][j] = __builtin_amdgcn_mfma_f32_16x16x32_bf16(af[i], bfr[j], acc[i][j], 0, 0, 0); \
    }                                                                          \
  } while (0)

  STAGE(0, 0);
  STAGE(1, 8192);
  asm volatile("s_waitcnt vmcnt(4)" ::: "memory");
  __syncthreads();
  COMPUTE(0);
  __syncthreads();
  STAGE(2, 0);
  asm volatile("s_waitcnt vmcnt(4)" ::: "memory");
  __syncthreads();
  COMPUTE(8192);
  __syncthreads();
  STAGE(3, 8192);
  asm volatile("s_waitcnt vmcnt(4)" ::: "memory");
  __syncthreads();
  COMPUTE(0);
  asm volatile("s_waitcnt vmcnt(0)" ::: "memory");
  __syncthreads();
  COMPUTE(8192);
#undef STAGE
#undef COMPUTE

  __syncthreads();
  float* Ef = (float*)SH;   // [row 128][132]
#pragma unroll
  for (int i = 0; i < 2; i++) {
    int ob = m0 + wr * 32 + i * 16 + g * 4;
    int lob = wr * 32 + i * 16 + g * 4;
    float bs0 = bias[ob + 0], bs1 = bias[ob + 1], bs2 = bias[ob + 2], bs3 = bias[ob + 3];
#pragma unroll
    for (int j = 0; j < 4; j++) {
      int lc = wc * 64 + j * 16 + q;
      Ef[(lob + 0) * 132 + lc] = acc[i][j][0] + bs0;
      Ef[(lob + 1) * 132 + lc] = acc[i][j][1] + bs1;
      Ef[(lob + 2) * 132 + lc] = acc[i][j][2] + bs2;
      Ef[(lob + 3) * 132 + lc] = acc[i][j][3] + bs3;
    }
  }
  __syncthreads();
  int rr = t >> 2, seg = t & 3;
  float* dst = outF + (size_t)b * M * N + (size_t)(m0 + rr) * N + n0;
#pragma unroll
  for (int k2 = 0; k2 < 8; k2++) {
    int col = seg * 32 + k2 * 4;
    if (n0 + col < N) {
      floatx4 v = *(const floatx4*)&Ef[rr * 132 + col];
      *(floatx4*)(dst + col) = v;
    }
  }
}

// ---------------- depthwise 3x3 on v (vb[b][px][256]), output vmt[b][ch][pixel] ----------------
__global__ __launch_bounds__(512) void k_dwconv_t(const unsigned short* __restrict__ vb,
                                                  const float* __restrict__ wdw,
                                                  const float* __restrict__ bdw,
                                                  unsigned short* __restrict__ vmt) {
  __shared__ float wS[1152];
  __shared__ float bS[128];
  __shared__ __align__(16) unsigned short tile[32][140];
  int t = threadIdx.x;
  int pass = blockIdx.y, b = blockIdx.z;
  for (int i = t; i < 1152; i += 512) wS[i] = wdw[pass * 1152 + i];
  if (t < 128) bS[t] = bdw[pass * 128 + t];
  __syncthreads();

  int pi = t >> 4, c8 = (t & 15) * 8;
  int i32 = blockIdx.x * 32 + pi;
  int h, w;
  if (pass == 0) { h = i32 / Wn; w = i32 % Wn; }
  else           { w = i32 / Hn; h = i32 % Hn; }

  const unsigned short* vq = vb + pass * 128 + c8;
  float a[8];
  short8 vc = *(const short8*)(vq + ((size_t)b * HWn + h * Wn + w) * 256);
#pragma unroll
  for (int e = 0; e < 8; e++) a[e] = bf2f((unsigned short)vc[e]) + bS[c8 + e];
#pragma unroll
  for (int ky = 0; ky < 3; ky++) {
    int hh = h + ky - 1;
    if (hh < 0 || hh >= Hn) continue;
#pragma unroll
    for (int kx = 0; kx < 3; kx++) {
      int ww = w + kx - 1;
      if (ww < 0 || ww >= Wn) continue;
      short8 vn = *(const short8*)(vq + ((size_t)b * HWn + hh * Wn + ww) * 256);
#pragma unroll
      for (int e = 0; e < 8; e++) a[e] += bf2f((unsigned short)vn[e]) * wS[(c8 + e) * 9 + ky * 3 + kx];
    }
  }
  short8 o;
#pragma unroll
  for (int e = 0; e < 8; e++) o[e] = (short)f2bf(a[e]);
  *(short8*)&tile[pi][c8] = o;
  __syncthreads();

  int dd = t >> 2, quarter = t & 3;
  short8 ov;
#pragma unroll
  for (int k2 = 0; k2 < 8; k2++) ov[k2] = (short)tile[quarter * 8 + k2][dd];
  *(short8*)(vmt + ((size_t)(b * Cn + pass * 128 + dd)) * HWn + blockIdx.x * 32 + quarter * 8) = ov;
}

// ---------------- stripe attention (two-phase scores: peak 52 score VGPRs) ----------------
// grid: (stripe 0..7, b*8+hd 0..63), 512 threads (8 waves)
__global__ __launch_bounds__(512) void k_attn(const unsigned short* __restrict__ qkh,
                                              const unsigned short* __restrict__ vmt,
                                              unsigned short* __restrict__ aout) {
  __shared__ __align__(16) unsigned short Ks[12288];  // 24 j * 4 g * 16 q granules
  __shared__ __align__(16) unsigned short Vf[12800];  // 50 Gc * 32 d granules (d swizzled)
  __shared__ __align__(16) unsigned short Pf[4096];   // 8 waves * 4 Gl * 16 q granules
  int s = blockIdx.x;
  int hd = blockIdx.y & 7, b = blockIdx.y >> 3;
  int t = threadIdx.x, lane = t & 63, wv = t >> 6;
  bool wst = (hd >= 4);
  int q = lane & 15, g = lane >> 4;
  int sbase = s * SEQ;

  const unsigned short* qh = qkh + (((size_t)b * 16 + hd) * HWn + sbase) * 32;
  const unsigned short* kh = qkh + (((size_t)b * 16 + 8 + hd) * HWn + sbase) * 32;

  // ---- Q prefetch ----
  short8 qpre[4];
#pragma unroll
  for (int it = 0; it < 4; it++) {
    int qb = it * 8 + wv;
    int qi = qb * 16 + q;
    int qil = (qi < SEQ) ? qi : 391;
    qpre[it] = *(const short8*)(qh + (size_t)qil * 32 + g * 8);
  }

  // ---- stage K keys 0..383, fragment-major ----
#pragma unroll
  for (int P = 0; P < 3; P++) {
    int key = P * 128 + (t >> 2);
    int gg = t & 3;
    short8 kv = *(const short8*)(kh + (size_t)key * 32 + gg * 8);
    *(short8*)&Ks[((((key >> 4) * 4 + gg) * 16) + (key & 15)) * 8] = kv;
  }
  short8 kf24;
  {
    int key = 384 + q; if (key > 391) key = 391;
    kf24 = *(const short8*)(kh + (size_t)key * 32 + g * 8);
  }
  // ---- stage V fragment-major with d-swizzle ----
  const unsigned short* vg = vmt + ((size_t)(b * Cn + hd * HDIM)) * HWn + sbase;
  for (int idx = t; idx < 1600; idx += 512) {
    int d = idx / 50, Gc = idx % 50;
    short8 vv = *(const short8*)(vg + (size_t)d * HWn + Gc * 8);
    *(short8*)&Vf[(Gc * 32 + (d ^ (Gc & 7))) * 8] = vv;
  }
  __syncthreads();

  floatx4 z4 = {0.f, 0.f, 0.f, 0.f};
  unsigned short* Pw = &Pf[wv * 512];
  int gh = g >> 1, ge = (g & 1) * 4;

#pragma unroll
  for (int it = 0; it < 4; it++) {
    int qb = it * 8 + wv;
    if (qb >= 25) continue;
    int qi = qb * 16 + q;
    int qil = (qi < SEQ) ? qi : 391;
    short8 qf = qpre[it];

    floatx4 sph[13];
    float sm = 0.f;
    floatx4 o0 = z4, o1 = z4;

// write P chunk for sacc pair (arrA, idxA valid; arrB may be the zero tail)
#define WRITEPX(sA_, sB_, validB) do {                                         \
    uint2 wA, wB;                                                              \
    wA.x = cvt_pk_bf16((sA_)[0], (sA_)[1]);                                    \
    wA.y = cvt_pk_bf16((sA_)[2], (sA_)[3]);                                    \
    if (validB) {                                                              \
      wB.x = cvt_pk_bf16((sB_)[0], (sB_)[1]);                                  \
      wB.y = cvt_pk_bf16((sB_)[2], (sB_)[3]);                                  \
    } else { wB.x = 0u; wB.y = 0u; }                                           \
    *(uint2*)&Pw[(gh * 16 + q) * 8 + ge] = wA;                                 \
    *(uint2*)&Pw[((2 + gh) * 16 + q) * 8 + ge] = wB;                           \
  } while (0)

#define PVSTEP(ch) do {                                                        \
    asm volatile("s_waitcnt lgkmcnt(0)" ::: "memory");                         \
    short8 pfr = *(const short8*)&Pw[(g * 16 + q) * 8];                        \
    int Gc = (ch) * 4 + g; if (Gc > 49) Gc = 49;                               \
    int sw = Gc & 7;                                                           \
    short8 vf0 = *(const short8*)&Vf[(Gc * 32 + (q ^ sw)) * 8];                \
    short8 vf1 = *(const short8*)&Vf[(Gc * 32 + 16 + (q ^ sw)) * 8];           \
    pfr_ = pfr; vf0_ = vf0; vf1_ = vf1;                                        \
  } while (0)

    short8 pfr_, vf0_, vf1_;

    // ======== phase A: j 0..11 (chunks 0..5) ========
    __builtin_amdgcn_s_setprio(1);
#pragma unroll
    for (int j = 0; j < 12; j++) {
      short8 kf = *(const short8*)&Ks[((j * 4 + g) * 16 + q) * 8];
      sph[j] = __builtin_amdgcn_mfma_f32_16x16x32_bf16(kf, qf, z4, 0, 0, 0);
    }
    __builtin_amdgcn_s_setprio(0);
#pragma unroll
    for (int j = 0; j < 12; j++) {
      float e0 = EXP2(sph[j][0]); float e1 = EXP2(sph[j][1]);
      float e2 = EXP2(sph[j][2]); float e3 = EXP2(sph[j][3]);
      sph[j][0] = e0; sph[j][1] = e1; sph[j][2] = e2; sph[j][3] = e3;
      sm += (e0 + e1) + (e2 + e3);
    }
    WRITEPX(sph[0], sph[1], true);
#pragma unroll
    for (int ch = 0; ch < 6; ch++) {
      PVSTEP(ch);
      if (ch < 5) {
        switch (ch + 1) {
          case 1: WRITEPX(sph[2], sph[3], true); break;
          case 2: WRITEPX(sph[4], sph[5], true); break;
          case 3: WRITEPX(sph[6], sph[7], true); break;
          case 4: WRITEPX(sph[8], sph[9], true); break;
          case 5: WRITEPX(sph[10], sph[11], true); break;
        }
      }
      __builtin_amdgcn_s_setprio(1);
      o0 = __builtin_amdgcn_mfma_f32_16x16x32_bf16(vf0_, pfr_, o0, 0, 0, 0);
      o1 = __builtin_amdgcn_mfma_f32_16x16x32_bf16(vf1_, pfr_, o1, 0, 0, 0);
      __builtin_amdgcn_s_setprio(0);
    }

    // ======== phase B: j 12..24 (chunks 6..12) ========
    __builtin_amdgcn_s_setprio(1);
#pragma unroll
    for (int j = 0; j < 12; j++) {
      short8 kf = *(const short8*)&Ks[(((j + 12) * 4 + g) * 16 + q) * 8];
      sph[j] = __builtin_amdgcn_mfma_f32_16x16x32_bf16(kf, qf, z4, 0, 0, 0);
    }
    sph[12] = __builtin_amdgcn_mfma_f32_16x16x32_bf16(kf24, qf, z4, 0, 0, 0);
    __builtin_amdgcn_s_setprio(0);
    if (g >= 2) { sph[12][0] = sph[12][1] = sph[12][2] = sph[12][3] = -3.0e38f; }
#pragma unroll
    for (int j = 0; j < 13; j++) {
      float e0 = EXP2(sph[j][0]); float e1 = EXP2(sph[j][1]);
      float e2 = EXP2(sph[j][2]); float e3 = EXP2(sph[j][3]);
      sph[j][0] = e0; sph[j][1] = e1; sph[j][2] = e2; sph[j][3] = e3;
      sm += (e0 + e1) + (e2 + e3);
    }
    WRITEPX(sph[0], sph[1], true);
#pragma unroll
    for (int ch = 6; ch < 13; ch++) {
      PVSTEP(ch);
      if (ch < 12) {
        switch (ch + 1) {
          case 7:  WRITEPX(sph[2], sph[3], true); break;
          case 8:  WRITEPX(sph[4], sph[5], true); break;
          case 9:  WRITEPX(sph[6], sph[7], true); break;
          case 10: WRITEPX(sph[8], sph[9], true); break;
          case 11: WRITEPX(sph[10], sph[11], true); break;
          case 12: WRITEPX(sph[12], sph[12], false); break;
        }
      }
      __builtin_amdgcn_s_setprio(1);
      o0 = __builtin_amdgcn_mfma_f32_16x16x32_bf16(vf0_, pfr_, o0, 0, 0, 0);
      o1 = __builtin_amdgcn_mfma_f32_16x16x32_bf16(vf1_, pfr_, o1, 0, 0, 0);
      __builtin_amdgcn_s_setprio(0);
    }
#undef WRITEPX
#undef PVSTEP

    sm += __shfl_xor(sm, 16);
    sm += __shfl_xor(sm, 32);
    float rcp = 1.0f / sm;

    if (qi < SEQ) {
      int pq = wst ? ((qil % Wn) * Wn + s * 7 + qil / Wn) : (sbase + qil);
      size_t ob = ((size_t)b * HWn + pq) * Cn + hd * HDIM;
      ushort4 u0, u1;
      u0.x = f2bf(o0[0] * rcp); u0.y = f2bf(o0[1] * rcp);
      u0.z = f2bf(o0[2] * rcp); u0.w = f2bf(o0[3] * rcp);
      u1.x = f2bf(o1[0] * rcp); u1.y = f2bf(o1[1] * rcp);
      u1.z = f2bf(o1[2] * rcp); u1.w = f2bf(o1[3] * rcp);
      *(ushort4*)(aout + ob + g * 4) = u0;
      *(ushort4*)(aout + ob + 16 + g * 4) = u1;
    }
  }
}

extern "C" void kernel_launch(void* const* d_in, const int* in_sizes, int n_in,
                              void* d_out, int out_size, void* d_ws, size_t ws_size,
                              hipStream_t stream) {
  const float* x     = (const float*)d_in[0];
  const float* wqkv  = (const float*)d_in[1];
  const float* bqkv  = (const float*)d_in[2];
  const float* wdw   = (const float*)d_in[3];
  const float* bdw   = (const float*)d_in[4];
  const float* wproj = (const float*)d_in[5];
  const float* bproj = (const float*)d_in[6];
  float* out = (float*)d_out;

  unsigned short* xt   = (unsigned short*)d_ws;                    // [B][HW][256] bf16
  unsigned short* wqb  = xt + (size_t)Bn * HWn * Cn;               // [768][256]
  unsigned short* wpb  = wqb + 768 * 256;                          // [256][256]
  unsigned short* qkh  = wpb + 256 * 256;                          // [B][16][HW][32] head-panels
  unsigned short* vb   = qkh + (size_t)Bn * 16 * HWn * 32;         // [B][HW][256] v pixel-major
  unsigned short* vmt  = vb + (size_t)Bn * HWn * Cn;               // [B][256ch][HW]
  unsigned short* aout = vmt + (size_t)Bn * HWn * Cn;              // [B][HW][256]

  k_prep<<<dim3(256 + 98 * 8 * Bn), 256, 0, stream>>>(wqkv, wproj, wqb, wpb, x, xt);
  k_gemm0<<<dim3(1200), 512, 0, stream>>>(wqb, xt, bqkv, qkh, vb);
  k_dwconv_t<<<dim3(98, 2, Bn), 512, 0, stream>>>(vb, wdw, bdw, vmt);
  k_attn<<<dim3(NSTR, Bn * NHEADS), 512, 0, stream>>>(qkh, vmt, aout);
  k_gemm1<<<dim3(400), 512, 0, stream>>>(wpb, aout, bproj, out, 256, HWn, 2, 50);
}

// Round 22
// 101.952 us; speedup vs baseline: 1.0333x; 1.0033x over previous
//
#include <hip/hip_runtime.h>
#include <hip/hip_bf16.h>
#include <stdint.h>

#define Bn 8
#define Cn 256
#define Hn 56
#define Wn 56
#define HWn 3136
#define NHEADS 8
#define HDIM 32
#define SEQ 392
#define NSTR 8
#define QKV_LD 768
// SCALE * log2(e): K is pre-scaled by this in the qkv-GEMM epilogue so the
// attention softmax can use exp2 with no per-score multiply.
#define KSC (0.17677669529663689f * 1.4426950408889634f)

#if __has_builtin(__builtin_amdgcn_exp2f)
#define EXP2(x) __builtin_amdgcn_exp2f(x)
#else
#define EXP2(x) exp2f(x)
#endif

typedef short short8 __attribute__((ext_vector_type(8)));
typedef float floatx4 __attribute__((ext_vector_type(4)));

__device__ __forceinline__ unsigned short f2bf(float f) {
  union { float f; uint32_t u; } v; v.f = f;
  uint32_t u = v.u;
  u += 0x7fffu + ((u >> 16) & 1u);   // RNE
  return (unsigned short)(u >> 16);
}
__device__ __forceinline__ float bf2f(unsigned short h) {
  union { uint32_t u; float f; } v; v.u = ((uint32_t)h) << 16;
  return v.f;
}
__device__ __forceinline__ uint32_t cvt_pk_bf16(float lo, float hi) {
  uint32_t r;
  asm("v_cvt_pk_bf16_f32 %0, %1, %2" : "=v"(r) : "v"(lo), "v"(hi));
  return r;
}
// async global->LDS, 16B per lane; LDS dest = wave-uniform base + lane*16
__device__ __forceinline__ void gload16(const unsigned short* g, unsigned short* l) {
  __builtin_amdgcn_global_load_lds((const __attribute__((address_space(1))) void*)g,
                                   (__attribute__((address_space(3))) void*)l, 16, 0, 0);
}

// ---------------- prep: weight cvt (blocks 0..255) + x transpose (blocks 256+) ----------------
__global__ __launch_bounds__(256) void k_prep(const float* __restrict__ wa,
                                              const float* __restrict__ wb,
                                              unsigned short* __restrict__ da,
                                              unsigned short* __restrict__ db,
                                              const float* __restrict__ x,
                                              unsigned short* __restrict__ xt) {
  int bx = blockIdx.x;
  int t = threadIdx.x;
  if (bx < 256) {
    int i = bx * 256 + t;   // 65536 float4 slots total
    if (i < 49152) {
      float4 v = ((const float4*)wa)[i];
      ushort4 o;
      o.x = f2bf(v.x); o.y = f2bf(v.y); o.z = f2bf(v.z); o.w = f2bf(v.w);
      ((ushort4*)da)[i] = o;
    } else {
      int k = i - 49152;
      float4 v = ((const float4*)wb)[k];
      ushort4 o;
      o.x = f2bf(v.x); o.y = f2bf(v.y); o.z = f2bf(v.z); o.w = f2bf(v.w);
      ((ushort4*)db)[k] = o;
    }
    return;
  }
  __shared__ float tile[32][33];
  int tx = bx - 256;
  int pb = tx % 98, cb = (tx / 98) & 7, b = tx / 784;
  int c = t >> 3, p4 = (t & 7) * 4;
  float4 v = *(const float4*)(x + (((size_t)b * Cn + cb * 32 + c) * HWn + pb * 32 + p4));
  tile[c][p4 + 0] = v.x; tile[c][p4 + 1] = v.y; tile[c][p4 + 2] = v.z; tile[c][p4 + 3] = v.w;
  __syncthreads();
  int p = t >> 3, c4 = (t & 7) * 4;
  ushort4 o;
  o.x = f2bf(tile[c4 + 0][p]); o.y = f2bf(tile[c4 + 1][p]);
  o.z = f2bf(tile[c4 + 2][p]); o.w = f2bf(tile[c4 + 3][p]);
  *(ushort4*)(xt + (((size_t)b * HWn + pb * 32 + p) * Cn + cb * 32 + c4)) = o;
}

// ---------------- qkv GEMM (M=768, K=256, BK=32): 32 KB LDS ----------------
__global__ __launch_bounds__(512) void k_gemm0(const unsigned short* __restrict__ A,
                                               const unsigned short* __restrict__ Bt,
                                               const float* __restrict__ bias,
                                               unsigned short* __restrict__ qkh,
                                               unsigned short* __restrict__ outV) {
  const int K = 256, N = HWn;
  __shared__ __align__(16) unsigned short SH[16384];   // As[2][4096] + Bs[2][4096]
  unsigned short* As = SH;
  unsigned short* Bs = SH + 8192;
  int t = threadIdx.x;
  int raw = blockIdx.x;
  int chunk = gridDim.x >> 3;
  int wg = (raw & 7) * chunk + (raw >> 3);     // bijective (grid % 8 == 0)
  int b = wg / 150, r = wg % 150;
  int m0 = (r % 6) * 128, n0 = (r / 6) * 128;
  const unsigned short* Bb = Bt + (size_t)b * N * K;
  int lane = t & 63, w = t >> 6;
  int wr = w >> 1, wc = w & 1;
  int g = lane >> 4, q = lane & 15;
  int rt = t >> 2, st = t & 3;                 // staging row / slot
  int cs = st ^ (rt & 3);
  const unsigned short* Ag = A + (size_t)(m0 + rt) * K + cs * 8;
  int nr = n0 + rt;
  const unsigned short* Bg = Bb + (size_t)((nr < N) ? nr : (N - 1)) * K + cs * 8;
  int ldst = t * 8;

  floatx4 z4 = {0.f, 0.f, 0.f, 0.f};
  floatx4 acc[2][4];
#pragma unroll
  for (int i = 0; i < 2; i++)
#pragma unroll
    for (int j = 0; j < 4; j++) acc[i][j] = z4;

#define STAGE0(kt, off) do {                                                   \
    gload16(Ag + (kt) * 32, &As[(off) + ldst]);                                \
    gload16(Bg + (kt) * 32, &Bs[(off) + ldst]);                                \
  } while (0)

#define COMPUTE0(off) do {                                                     \
    short8 af[2], bfr[4];                                                      \
    _Pragma("unroll")                                                          \
    for (int i = 0; i < 2; i++) {                                              \
      int row = wr * 32 + i * 16 + q;                                          \
      af[i] = *(const short8*)&As[(off) + row * 32 + ((g ^ (q & 3)) << 3)];    \
    }                                                                          \
    _Pragma("unroll")                                                          \
    for (int j = 0; j < 4; j++) {                                              \
      int row = wc * 64 + j * 16 + q;                                          \
      bfr[j] = *(const short8*)&Bs[(off) + row * 32 + ((g ^ (q & 3)) << 3)];   \
    }                                                                          \
    _Pragma("unroll")                                                          \
    for (int i = 0; i < 2; i++)                                                \
      _Pragma("unroll")                                                        \
      for (int j = 0; j < 4; j++)                                              \
        acc[i][j] = __builtin_amdgcn_mfma_f32_16x16x32_bf16(af[i], bfr[j], acc[i][j], 0, 0, 0); \
  } while (0)

  STAGE0(0, 0);
  STAGE0(1, 4096);
#pragma unroll
  for (int tt = 0; tt < 8; tt++) {
    if (tt < 7) { asm volatile("s_waitcnt vmcnt(2)" ::: "memory"); }
    else       { asm volatile("s_waitcnt vmcnt(0)" ::: "memory"); }
    __syncthreads();
    COMPUTE0((tt & 1) * 4096);
    __syncthreads();
    if (tt < 6) STAGE0(tt + 2, (tt & 1) * 4096);
  }
#undef STAGE0
#undef COMPUTE0

  // ---- LDS-transposed epilogue: E[col 128][16 granules x 8ch], XOR-swizzled ----
  unsigned short* E = SH;   // 32768 B, exactly fits
#pragma unroll
  for (int i = 0; i < 2; i++) {
    int ob = m0 + wr * 32 + i * 16 + g * 4;
    float bs0 = bias[ob + 0], bs1 = bias[ob + 1], bs2 = bias[ob + 2], bs3 = bias[ob + 3];
    float sc = (ob >= 256 && ob < 512) ? KSC : 1.0f;
    int lobg = wr * 4 + i * 2 + (g >> 1);
#pragma unroll
    for (int j = 0; j < 4; j++) {
      int lc = wc * 64 + j * 16 + q;
      ushort4 o;
      o.x = f2bf((acc[i][j][0] + bs0) * sc);
      o.y = f2bf((acc[i][j][1] + bs1) * sc);
      o.z = f2bf((acc[i][j][2] + bs2) * sc);
      o.w = f2bf((acc[i][j][3] + bs3) * sc);
      *(ushort4*)&E[lc * 128 + ((lobg ^ (lc & 7)) << 3) + (g & 1) * 4] = o;
    }
  }
  __syncthreads();
  int c = t >> 2, part = t & 3;
  int col = n0 + c;
  if (col < N) {
    int mt = m0 >> 7;            // 0..5
    unsigned short* dst;
    if (mt < 4) {                // q,k head-panels
      int hd = (mt & 1) * 4 + part;
      int sl = (mt >> 1) * 8 + hd;           // isK*8 + head
      int p_ord = (hd >= 4) ? ((col % Wn) * Wn + col / Wn) : col;
      dst = qkh + (((size_t)b * 16 + sl) * HWn + p_ord) * 32;
    } else {                     // v pixel-major
      dst = outV + ((size_t)b * HWn + col) * 256 + (m0 - 512) + part * 32;
    }
#pragma unroll
    for (int k2 = part * 4; k2 < part * 4 + 4; k2++) {   // 32 chans = 64B contiguous
      short8 v = *(const short8*)&E[c * 128 + ((k2 ^ (c & 7)) << 3)];
      *(short8*)(dst + (k2 - part * 4) * 8) = v;
    }
  }
}

// ---------------- proj GEMM (M=256, K=256, BK=64) ----------------
__global__ __launch_bounds__(512) void k_gemm1(const unsigned short* __restrict__ A,
                                               const unsigned short* __restrict__ Bt,
                                               const float* __restrict__ bias,
                                               float* __restrict__ outF,
                                               int M, int N, int nm, int nper) {
  const int K = 256;
  __shared__ __align__(16) char SH[67584];
  unsigned short* As = (unsigned short*)SH;   // [2][8192]
  unsigned short* Bs = As + 16384;            // [2][8192]
  int t = threadIdx.x;
  int raw = blockIdx.x;
  int chunk = gridDim.x >> 3;
  int wg = (raw & 7) * chunk + (raw >> 3);
  int b = wg / nper, r = wg % nper;
  int m0 = (r % nm) * 128, n0 = (r / nm) * 128;
  const unsigned short* Bb = Bt + (size_t)b * N * K;
  int lane = t & 63, w = t >> 6;
  int wr = w >> 1, wc = w & 1;
  int g = lane >> 4, q = lane & 15;
  int srow8 = lane >> 3;
  int slot = lane & 7;

  const unsigned short* Ag[2];
  const unsigned short* Bg[2];
  int ldst[2];
#pragma unroll
  for (int i = 0; i < 2; i++) {
    int row = i * 64 + w * 8 + srow8;
    int cs = slot ^ srow8;
    Ag[i] = A + (size_t)(m0 + row) * K + cs * 8;
    int nr = n0 + row;
    Bg[i] = Bb + (size_t)((nr < N) ? nr : (N - 1)) * K + cs * 8;
    ldst[i] = (i * 64 + w * 8) * 64;
  }

  floatx4 z4 = {0.f, 0.f, 0.f, 0.f};
  floatx4 acc[2][4];
#pragma unroll
  for (int i = 0; i < 2; i++)
#pragma unroll
    for (int j = 0; j < 4; j++) acc[i][j] = z4;

#define STAGE(kt, off) do {                                                    \
    _Pragma("unroll")                                                          \
    for (int i = 0; i < 2; i++) gload16(Ag[i] + (kt) * 64, &As[(off) + ldst[i]]); \
    _Pragma("unroll")                                                          \
    for (int i = 0; i < 2; i++) gload16(Bg[i] + (kt) * 64, &Bs[(off) + ldst[i]]); \
  } while (0)

#define COMPUTE(off) do {                                                      \
    _Pragma("unroll")                                                          \
    for (int kk = 0; kk < 64; kk += 32) {                                      \
      short8 af[2], bfr[4];                                                    \
      _Pragma("unroll")                                                        \
      for (int i = 0; i < 2; i++) {                                            \
        int row = wr * 32 + i * 16 + q;                                        \
        af[i] = *(const short8*)&As[(off) + row * 64 + ((((kk >> 3) + g) ^ (q & 7)) << 3)]; \
      }                                                                        \
      _Pragma("unroll")                                                        \
      for (int j = 0; j < 4; j++) {                                            \
        int row = wc * 64 + j * 16 + q;                                        \
        bfr[j] = *(const short8*)&Bs[(off) + row * 64 + ((((kk >> 3) + g) ^ (q & 7)) << 3)]; \
      }                                                                        \
      _Pragma("unroll")                                                        \
      for (int i = 0; i < 2; i++)                                              \
        _Pragma("unroll")                                                      \
        for (int j = 0; j < 4; j++)                                            \
          acc[i][j] = __builtin_amdgcn_mfma_f32_16x16x32_bf16(af[i], bfr[j], acc[i][j], 0, 0, 0); \
    }                                                                          \
  } while (0)

  STAGE(0, 0);
  STAGE(1, 8192);
  asm volatile("s_waitcnt vmcnt(4)" ::: "memory");
  __syncthreads();
  COMPUTE(0);
  __syncthreads();
  STAGE(2, 0);
  asm volatile("s_waitcnt vmcnt(4)" ::: "memory");
  __syncthreads();
  COMPUTE(8192);
  __syncthreads();
  STAGE(3, 8192);
  asm volatile("s_waitcnt vmcnt(4)" ::: "memory");
  __syncthreads();
  COMPUTE(0);
  asm volatile("s_waitcnt vmcnt(0)" ::: "memory");
  __syncthreads();
  COMPUTE(8192);
#undef STAGE
#undef COMPUTE

  __syncthreads();
  float* Ef = (float*)SH;   // [row 128][132]
#pragma unroll
  for (int i = 0; i < 2; i++) {
    int ob = m0 + wr * 32 + i * 16 + g * 4;
    int lob = wr * 32 + i * 16 + g * 4;
    float bs0 = bias[ob + 0], bs1 = bias[ob + 1], bs2 = bias[ob + 2], bs3 = bias[ob + 3];
#pragma unroll
    for (int j = 0; j < 4; j++) {
      int lc = wc * 64 + j * 16 + q;
      Ef[(lob + 0) * 132 + lc] = acc[i][j][0] + bs0;
      Ef[(lob + 1) * 132 + lc] = acc[i][j][1] + bs1;
      Ef[(lob + 2) * 132 + lc] = acc[i][j][2] + bs2;
      Ef[(lob + 3) * 132 + lc] = acc[i][j][3] + bs3;
    }
  }
  __syncthreads();
  int rr = t >> 2, seg = t & 3;
  float* dst = outF + (size_t)b * M * N + (size_t)(m0 + rr) * N + n0;
#pragma unroll
  for (int k2 = 0; k2 < 8; k2++) {
    int col = seg * 32 + k2 * 4;
    if (n0 + col < N) {
      floatx4 v = *(const floatx4*)&Ef[rr * 132 + col];
      *(floatx4*)(dst + col) = v;
    }
  }
}

// ---------------- depthwise 3x3 on v (vb[b][px][256]), output vmt[b][ch][pixel] ----------------
__global__ __launch_bounds__(512) void k_dwconv_t(const unsigned short* __restrict__ vb,
                                                  const float* __restrict__ wdw,
                                                  const float* __restrict__ bdw,
                                                  unsigned short* __restrict__ vmt) {
  __shared__ float wS[1152];
  __shared__ float bS[128];
  __shared__ __align__(16) unsigned short tile[32][140];
  int t = threadIdx.x;
  int pass = blockIdx.y, b = blockIdx.z;
  for (int i = t; i < 1152; i += 512) wS[i] = wdw[pass * 1152 + i];
  if (t < 128) bS[t] = bdw[pass * 128 + t];
  __syncthreads();

  int pi = t >> 4, c8 = (t & 15) * 8;
  int i32 = blockIdx.x * 32 + pi;
  int h, w;
  if (pass == 0) { h = i32 / Wn; w = i32 % Wn; }
  else           { w = i32 / Hn; h = i32 % Hn; }

  const unsigned short* vq = vb + pass * 128 + c8;
  float a[8];
  short8 vc = *(const short8*)(vq + ((size_t)b * HWn + h * Wn + w) * 256);
#pragma unroll
  for (int e = 0; e < 8; e++) a[e] = bf2f((unsigned short)vc[e]) + bS[c8 + e];
#pragma unroll
  for (int ky = 0; ky < 3; ky++) {
    int hh = h + ky - 1;
    if (hh < 0 || hh >= Hn) continue;
#pragma unroll
    for (int kx = 0; kx < 3; kx++) {
      int ww = w + kx - 1;
      if (ww < 0 || ww >= Wn) continue;
      short8 vn = *(const short8*)(vq + ((size_t)b * HWn + hh * Wn + ww) * 256);
#pragma unroll
      for (int e = 0; e < 8; e++) a[e] += bf2f((unsigned short)vn[e]) * wS[(c8 + e) * 9 + ky * 3 + kx];
    }
  }
  short8 o;
#pragma unroll
  for (int e = 0; e < 8; e++) o[e] = (short)f2bf(a[e]);
  *(short8*)&tile[pi][c8] = o;
  __syncthreads();

  int dd = t >> 2, quarter = t & 3;
  short8 ov;
#pragma unroll
  for (int k2 = 0; k2 < 8; k2++) ov[k2] = (short)tile[quarter * 8 + k2][dd];
  *(short8*)(vmt + ((size_t)(b * Cn + pass * 128 + dd)) * HWn + blockIdx.x * 32 + quarter * 8) = ov;
}

// ---------------- stripe attention (two-phase scores; compiler-managed LDS waits) ----------------
// grid: (stripe 0..7, b*8+hd 0..63), 512 threads (8 waves)
__global__ __launch_bounds__(512) void k_attn(const unsigned short* __restrict__ qkh,
                                              const unsigned short* __restrict__ vmt,
                                              unsigned short* __restrict__ aout) {
  __shared__ __align__(16) unsigned short Ks[12288];  // 24 j * 4 g * 16 q granules
  __shared__ __align__(16) unsigned short Vf[12800];  // 50 Gc * 32 d granules (d swizzled)
  __shared__ __align__(16) unsigned short Pf[4096];   // 8 waves * 4 Gl * 16 q granules
  int s = blockIdx.x;
  int hd = blockIdx.y & 7, b = blockIdx.y >> 3;
  int t = threadIdx.x, lane = t & 63, wv = t >> 6;
  bool wst = (hd >= 4);
  int q = lane & 15, g = lane >> 4;
  int sbase = s * SEQ;

  const unsigned short* qh = qkh + (((size_t)b * 16 + hd) * HWn + sbase) * 32;
  const unsigned short* kh = qkh + (((size_t)b * 16 + 8 + hd) * HWn + sbase) * 32;

  // ---- Q prefetch ----
  short8 qpre[4];
#pragma unroll
  for (int it = 0; it < 4; it++) {
    int qb = it * 8 + wv;
    int qi = qb * 16 + q;
    int qil = (qi < SEQ) ? qi : 391;
    qpre[it] = *(const short8*)(qh + (size_t)qil * 32 + g * 8);
  }

  // ---- stage K keys 0..383, fragment-major ----
#pragma unroll
  for (int P = 0; P < 3; P++) {
    int key = P * 128 + (t >> 2);
    int gg = t & 3;
    short8 kv = *(const short8*)(kh + (size_t)key * 32 + gg * 8);
    *(short8*)&Ks[((((key >> 4) * 4 + gg) * 16) + (key & 15)) * 8] = kv;
  }
  short8 kf24;
  {
    int key = 384 + q; if (key > 391) key = 391;
    kf24 = *(const short8*)(kh + (size_t)key * 32 + g * 8);
  }
  // ---- stage V fragment-major with d-swizzle ----
  const unsigned short* vg = vmt + ((size_t)(b * Cn + hd * HDIM)) * HWn + sbase;
  for (int idx = t; idx < 1600; idx += 512) {
    int d = idx / 50, Gc = idx % 50;
    short8 vv = *(const short8*)(vg + (size_t)d * HWn + Gc * 8);
    *(short8*)&Vf[(Gc * 32 + (d ^ (Gc & 7))) * 8] = vv;
  }
  __syncthreads();

  floatx4 z4 = {0.f, 0.f, 0.f, 0.f};
  unsigned short* Pw = &Pf[wv * 512];
  int gh = g >> 1, ge = (g & 1) * 4;

#pragma unroll
  for (int it = 0; it < 4; it++) {
    int qb = it * 8 + wv;
    if (qb >= 25) continue;
    int qi = qb * 16 + q;
    int qil = (qi < SEQ) ? qi : 391;
    short8 qf = qpre[it];

    floatx4 sph[13];
    float sm = 0.f;
    floatx4 o0 = z4, o1 = z4;

// write P chunk for sacc pair (arrA, idxA valid; arrB may be the zero tail)
#define WRITEPX(sA_, sB_, validB) do {                                         \
    uint2 wA, wB;                                                              \
    wA.x = cvt_pk_bf16((sA_)[0], (sA_)[1]);                                    \
    wA.y = cvt_pk_bf16((sA_)[2], (sA_)[3]);                                    \
    if (validB) {                                                              \
      wB.x = cvt_pk_bf16((sB_)[0], (sB_)[1]);                                  \
      wB.y = cvt_pk_bf16((sB_)[2], (sB_)[3]);                                  \
    } else { wB.x = 0u; wB.y = 0u; }                                           \
    *(uint2*)&Pw[(gh * 16 + q) * 8 + ge] = wA;                                 \
    *(uint2*)&Pw[((2 + gh) * 16 + q) * 8 + ge] = wB;                           \
  } while (0)

// NOTE: no explicit lgkmcnt drain here. DS ops are in-order per wave and the
// P write/read alias through Pw, so program order is preserved; the compiler
// inserts minimal counted lgkmcnt before each use (G7). The old lgkmcnt(0)
// forced 52 full LDS drains per wave, serializing independent V reads.
#define PVSTEP(ch) do {                                                        \
    short8 pfr = *(const short8*)&Pw[(g * 16 + q) * 8];                        \
    int Gc = (ch) * 4 + g; if (Gc > 49) Gc = 49;                               \
    int sw = Gc & 7;                                                           \
    short8 vf0 = *(const short8*)&Vf[(Gc * 32 + (q ^ sw)) * 8];                \
    short8 vf1 = *(const short8*)&Vf[(Gc * 32 + 16 + (q ^ sw)) * 8];           \
    pfr_ = pfr; vf0_ = vf0; vf1_ = vf1;                                        \
  } while (0)

    short8 pfr_, vf0_, vf1_;

    // ======== phase A: j 0..11 (chunks 0..5) ========
    __builtin_amdgcn_s_setprio(1);
#pragma unroll
    for (int j = 0; j < 12; j++) {
      short8 kf = *(const short8*)&Ks[((j * 4 + g) * 16 + q) * 8];
      sph[j] = __builtin_amdgcn_mfma_f32_16x16x32_bf16(kf, qf, z4, 0, 0, 0);
    }
    __builtin_amdgcn_s_setprio(0);
#pragma unroll
    for (int j = 0; j < 12; j++) {
      float e0 = EXP2(sph[j][0]); float e1 = EXP2(sph[j][1]);
      float e2 = EXP2(sph[j][2]); float e3 = EXP2(sph[j][3]);
      sph[j][0] = e0; sph[j][1] = e1; sph[j][2] = e2; sph[j][3] = e3;
      sm += (e0 + e1) + (e2 + e3);
    }
    WRITEPX(sph[0], sph[1], true);
#pragma unroll
    for (int ch = 0; ch < 6; ch++) {
      PVSTEP(ch);
      if (ch < 5) {
        switch (ch + 1) {
          case 1: WRITEPX(sph[2], sph[3], true); break;
          case 2: WRITEPX(sph[4], sph[5], true); break;
          case 3: WRITEPX(sph[6], sph[7], true); break;
          case 4: WRITEPX(sph[8], sph[9], true); break;
          case 5: WRITEPX(sph[10], sph[11], true); break;
        }
      }
      __builtin_amdgcn_s_setprio(1);
      o0 = __builtin_amdgcn_mfma_f32_16x16x32_bf16(vf0_, pfr_, o0, 0, 0, 0);
      o1 = __builtin_amdgcn_mfma_f32_16x16x32_bf16(vf1_, pfr_, o1, 0, 0, 0);
      __builtin_amdgcn_s_setprio(0);
    }

    // ======== phase B: j 12..24 (chunks 6..12) ========
    __builtin_amdgcn_s_setprio(1);
#pragma unroll
    for (int j = 0; j < 12; j++) {
      short8 kf = *(const short8*)&Ks[(((j + 12) * 4 + g) * 16 + q) * 8];
      sph[j] = __builtin_amdgcn_mfma_f32_16x16x32_bf16(kf, qf, z4, 0, 0, 0);
    }
    sph[12] = __builtin_amdgcn_mfma_f32_16x16x32_bf16(kf24, qf, z4, 0, 0, 0);
    __builtin_amdgcn_s_setprio(0);
    if (g >= 2) { sph[12][0] = sph[12][1] = sph[12][2] = sph[12][3] = -3.0e38f; }
#pragma unroll
    for (int j = 0; j < 13; j++) {
      float e0 = EXP2(sph[j][0]); float e1 = EXP2(sph[j][1]);
      float e2 = EXP2(sph[j][2]); float e3 = EXP2(sph[j][3]);
      sph[j][0] = e0; sph[j][1] = e1; sph[j][2] = e2; sph[j][3] = e3;
      sm += (e0 + e1) + (e2 + e3);
    }
    WRITEPX(sph[0], sph[1], true);
#pragma unroll
    for (int ch = 6; ch < 13; ch++) {
      PVSTEP(ch);
      if (ch < 12) {
        switch (ch + 1) {
          case 7:  WRITEPX(sph[2], sph[3], true); break;
          case 8:  WRITEPX(sph[4], sph[5], true); break;
          case 9:  WRITEPX(sph[6], sph[7], true); break;
          case 10: WRITEPX(sph[8], sph[9], true); break;
          case 11: WRITEPX(sph[10], sph[11], true); break;
          case 12: WRITEPX(sph[12], sph[12], false); break;
        }
      }
      __builtin_amdgcn_s_setprio(1);
      o0 = __builtin_amdgcn_mfma_f32_16x16x32_bf16(vf0_, pfr_, o0, 0, 0, 0);
      o1 = __builtin_amdgcn_mfma_f32_16x16x32_bf16(vf1_, pfr_, o1, 0, 0, 0);
      __builtin_amdgcn_s_setprio(0);
    }
#undef WRITEPX
#undef PVSTEP

    sm += __shfl_xor(sm, 16);
    sm += __shfl_xor(sm, 32);
    float rcp = 1.0f / sm;

    if (qi < SEQ) {
      int pq = wst ? ((qil % Wn) * Wn + s * 7 + qil / Wn) : (sbase + qil);
      size_t ob = ((size_t)b * HWn + pq) * Cn + hd * HDIM;
      ushort4 u0, u1;
      u0.x = f2bf(o0[0] * rcp); u0.y = f2bf(o0[1] * rcp);
      u0.z = f2bf(o0[2] * rcp); u0.w = f2bf(o0[3] * rcp);
      u1.x = f2bf(o1[0] * rcp); u1.y = f2bf(o1[1] * rcp);
      u1.z = f2bf(o1[2] * rcp); u1.w = f2bf(o1[3] * rcp);
      *(ushort4*)(aout + ob + g * 4) = u0;
      *(ushort4*)(aout + ob + 16 + g * 4) = u1;
    }
  }
}

extern "C" void kernel_launch(void* const* d_in, const int* in_sizes, int n_in,
                              void* d_out, int out_size, void* d_ws, size_t ws_size,
                              hipStream_t stream) {
  const float* x     = (const float*)d_in[0];
  const float* wqkv  = (const float*)d_in[1];
  const float* bqkv  = (const float*)d_in[2];
  const float* wdw   = (const float*)d_in[3];
  const float* bdw   = (const float*)d_in[4];
  const float* wproj = (const float*)d_in[5];
  const float* bproj = (const float*)d_in[6];
  float* out = (float*)d_out;

  unsigned short* xt   = (unsigned short*)d_ws;                    // [B][HW][256] bf16
  unsigned short* wqb  = xt + (size_t)Bn * HWn * Cn;               // [768][256]
  unsigned short* wpb  = wqb + 768 * 256;                          // [256][256]
  unsigned short* qkh  = wpb + 256 * 256;                          // [B][16][HW][32] head-panels
  unsigned short* vb   = qkh + (size_t)Bn * 16 * HWn * 32;         // [B][HW][256] v pixel-major
  unsigned short* vmt  = vb + (size_t)Bn * HWn * Cn;               // [B][256ch][HW]
  unsigned short* aout = vmt + (size_t)Bn * HWn * Cn;              // [B][HW][256]

  k_prep<<<dim3(256 + 98 * 8 * Bn), 256, 0, stream>>>(wqkv, wproj, wqb, wpb, x, xt);
  k_gemm0<<<dim3(1200), 512, 0, stream>>>(wqb, xt, bqkv, qkh, vb);
  k_dwconv_t<<<dim3(98, 2, Bn), 512, 0, stream>>>(vb, wdw, bdw, vmt);
  k_attn<<<dim3(NSTR, Bn * NHEADS), 512, 0, stream>>>(qkh, vmt, aout);
  k_gemm1<<<dim3(400), 512, 0, stream>>>(wpb, aout, bproj, out, 256, HWn, 2, 50);
}